// Round 3
// baseline (512.552 us; speedup 1.0000x reference)
//
#include <hip/hip_runtime.h>
#include <hip/hip_bf16.h>

#define NPTS 150
#define KP   168          // padded K for MFMA; 5 K-steps of 32 cover 0..159
#define NPAR 193
#define OSTR 388

// bf16 transposed activation buffers, element offsets into sT
#define H1T  0            // [11][168]  rows 0..9 = h1^T, row 10 = ones (db2)
#define H2T  1848         // [11][168]  rows 0..9 = h2^T, row 10 = ones (db3)
#define XT   3696         // [5][168]   rows 0..3 = x^T,  row 4  = ones (db1)
#define DZ2T 4536         // [10][168]
#define DZ1T 6216         // [10][168]
#define DLT  7896         // [3][168]
#define TTOT 8400

typedef __attribute__((ext_vector_type(8))) short short8;
typedef __attribute__((ext_vector_type(4))) float f32x4;

__constant__ float LRS[6] = {0.001f, 0.01f, 0.05f, 0.1f, 0.5f, 1.0f};

// 192 threads = 3 waves per MLP. Each thread owns one data point (t<150).
// Wave w handles one dW MFMA tile.
// NOTE: sT must be FULLY zeroed before MFMA: pad cols are read by the MFMA on
// both A and B sides, and uninitialized LDS as bf16 can be Inf/NaN (0*Inf=NaN).
__global__ __launch_bounds__(192, 4) void mlp_kernelA(
    const float* __restrict__ W1, const float* __restrict__ b1,
    const float* __restrict__ W2, const float* __restrict__ b2,
    const float* __restrict__ W3, const float* __restrict__ b3,
    const float* __restrict__ G1, const float* __restrict__ G2,
    const float* __restrict__ G3, const float* __restrict__ G4,
    const float* __restrict__ G5, const float* __restrict__ G6,
    const float* __restrict__ dx, const float* __restrict__ fv,
    const int* __restrict__ dy, const int* __restrict__ stepsz,
    float* __restrict__ out, float* __restrict__ slots)
{
    const int m    = blockIdx.x;
    const int t    = threadIdx.x;
    const int lane = t & 63;
    const int w    = t >> 6;

    __shared__ alignas(16) __hip_bfloat16 sT[TTOT];
    __shared__ alignas(16) float sP[200];
    __shared__ float red[8];

    const float lr = LRS[stepsz[m]];

    // ---- SGD update: each thread computes param index t (t=0 also does 192) ----
    float pv;
    if      (t < 40)  pv = W1[m*40 + t]        - lr * G1[m*40 + t];
    else if (t < 50)  pv = b1[m*10 + (t-40)]   - lr * G2[m*10 + (t-40)];
    else if (t < 150) pv = W2[m*100 + (t-50)]  - lr * G3[m*100 + (t-50)];
    else if (t < 160) pv = b2[m*10 + (t-150)]  - lr * G4[m*10 + (t-150)];
    else if (t < 190) pv = W3[m*30 + (t-160)]  - lr * G5[m*30 + (t-160)];
    else              pv = b3[m*3 + (t-190)]   - lr * G6[m*3 + (t-190)];
    sP[t] = pv;
    out[(size_t)m*OSTR + t] = fminf(fmaxf(pv, -10000.f), 10000.f);
    if (t == 0) {
        float p192 = b3[m*3 + 2] - lr * G6[m*3 + 2];
        sP[192] = p192;
        out[(size_t)m*OSTR + 192] = fminf(fmaxf(p192, -10000.f), 10000.f);
    }

    // ---- zero the whole bf16 T-buffer (pad cols MUST be finite zeros) ----
    {
        f32x4 z = {0.f, 0.f, 0.f, 0.f};
        f32x4* p = (f32x4*)sT;                 // 8400 bf16 = 1050 x 16B
        for (int i = t; i < 1050; i += 192) p[i] = z;
    }
    __syncthreads();

    // ---- ones rows (bias-grad columns) ----
    if (t < KP) {
        __hip_bfloat16 one = __float2bfloat16(1.0f);
        sT[H1T + 10*KP + t] = one;
        sT[H2T + 10*KP + t] = one;
        sT[XT  +  4*KP + t] = one;
    }
    // ---- x^T fill: x^T[f][n] = x[n][f] ----
    for (int i = t; i < 600; i += 192) {
        int n = i >> 2, f = i & 3;
        sT[XT + f*KP + n] = __float2bfloat16(dx[i]);
    }

    // ---- per-wave preload of wave-uniform params (broadcast LDS reads) ----
    float w2[10][10], bb2[10], w3[3][10], bb3[3], bb1[10];
    #pragma unroll
    for (int g = 0; g < 10; g++) {
        #pragma unroll
        for (int h = 0; h < 10; h++) w2[g][h] = sP[50 + g*10 + h];
        bb2[g] = sP[150 + g];
        bb1[g] = sP[40 + g];
    }
    #pragma unroll
    for (int o = 0; o < 3; o++) {
        #pragma unroll
        for (int g = 0; g < 10; g++) w3[o][g] = sP[160 + o*10 + g];
        bb3[o] = sP[190 + o];
    }
    const f32x4* sP4 = (const f32x4*)sP;   // W1 row j at sP4[j]

    // ================= fused forward + backward-dz: ONE point per thread =====
    float lossacc = 0.f, ssacc = 0.f;
    {
        const int  n   = t;
        const bool act = (n < NPTS);
        const int  nc  = act ? n : 0;

        f32x4 xv = ((const f32x4*)dx)[nc];
        int   yv = dy[nc];

        float h1v[10];
        #pragma unroll
        for (int j = 0; j < 10; j++) {
            f32x4 wv = sP4[j];
            float z = bb1[j] + xv.x*wv.x + xv.y*wv.y + xv.z*wv.z + xv.w*wv.w;
            h1v[j] = fmaxf(z, 0.f);
        }
        float h2v[10];
        #pragma unroll
        for (int g = 0; g < 10; g++) {
            float z = bb2[g];
            #pragma unroll
            for (int h = 0; h < 10; h++) z += h1v[h] * w2[g][h];
            h2v[g] = fmaxf(z, 0.f);
        }
        float lg[3];
        #pragma unroll
        for (int o = 0; o < 3; o++) {
            float z = bb3[o];
            #pragma unroll
            for (int g = 0; g < 10; g++) z += h2v[g] * w3[o][g];
            lg[o] = z;
        }
        float mx = fmaxf(lg[0], fmaxf(lg[1], lg[2]));
        float e0 = __expf(lg[0]-mx), e1 = __expf(lg[1]-mx), e2 = __expf(lg[2]-mx);
        float s   = e0 + e1 + e2;
        float inv = 1.f / s;
        float lse = mx + __logf(s);
        float ly  = (yv == 0) ? lg[0] : ((yv == 1) ? lg[1] : lg[2]);
        lossacc = act ? (lse - ly) : 0.f;

        float dl[3];
        dl[0] = (e0*inv - ((yv==0)?1.f:0.f)) * (1.f/150.f);
        dl[1] = (e1*inv - ((yv==1)?1.f:0.f)) * (1.f/150.f);
        dl[2] = (e2*inv - ((yv==2)?1.f:0.f)) * (1.f/150.f);

        float dz2v[10];
        #pragma unroll
        for (int g = 0; g < 10; g++) {
            float d = dl[0]*w3[0][g] + dl[1]*w3[1][g] + dl[2]*w3[2][g];
            dz2v[g] = (h2v[g] > 0.f) ? d : 0.f;
        }
        float dz1v[10];
        #pragma unroll
        for (int h = 0; h < 10; h++) {
            float d = 0.f;
            #pragma unroll
            for (int g = 0; g < 10; g++) d += dz2v[g] * w2[g][h];
            dz1v[h] = (h1v[h] > 0.f) ? d : 0.f;
        }

        if (act) {
            #pragma unroll
            for (int j = 0; j < 10; j++) sT[H1T  + j*KP + n] = __float2bfloat16(h1v[j]);
            #pragma unroll
            for (int g = 0; g < 10; g++) sT[H2T  + g*KP + n] = __float2bfloat16(h2v[g]);
            #pragma unroll
            for (int o = 0; o < 3;  o++) sT[DLT  + o*KP + n] = __float2bfloat16(dl[o]);
            #pragma unroll
            for (int g = 0; g < 10; g++) sT[DZ2T + g*KP + n] = __float2bfloat16(dz2v[g]);
            #pragma unroll
            for (int h = 0; h < 10; h++) sT[DZ1T + h*KP + n] = __float2bfloat16(dz1v[h]);
        }
    }
    __syncthreads();

    // ================= weight-grad GEMMs via MFMA: one tile per wave =========
    {
        const short* sTs = reinterpret_cast<const short*>(sT);
        const int mrow = lane & 15, q = lane >> 4;

        int abase, arows, bbase, bcols, woff, nW, boff;
        if      (w == 0) { abase=DZ2T; arows=10; bbase=H1T; bcols=11; woff=50;  nW=10; boff=150; }
        else if (w == 1) { abase=DZ1T; arows=10; bbase=XT;  bcols=5;  woff=0;   nW=4;  boff=40;  }
        else             { abase=DLT;  arows=3;  bbase=H2T; bcols=11; woff=160; nW=10; boff=190; }

        int ar = (mrow < arows) ? mrow : 0;
        int br = (mrow < bcols) ? mrow : 0;
        f32x4 acc = {0.f, 0.f, 0.f, 0.f};
        #pragma unroll
        for (int kk = 0; kk < 5; kk++) {
            int k0 = kk*32 + q*8;
            short8 a = *(const short8*)(sTs + abase + ar*KP + k0);
            short8 b = *(const short8*)(sTs + bbase + br*KP + k0);
            acc = __builtin_amdgcn_mfma_f32_16x16x32_bf16(a, b, acc, 0, 0, 0);
        }
        #pragma unroll
        for (int r = 0; r < 4; r++) {
            int row = q*4 + r;
            if (row < arows && mrow < bcols) {
                float v = acc[r];
                int off = (mrow < nW) ? (woff + row*nW + mrow) : (boff + row);
                out[(size_t)m*OSTR + NPAR + off] = v;   // raw grad; kernel C scales
                ssacc += v*v;
            }
        }
    }

    // ---- reductions: loss (across all 3 waves), sumsq (per-wave tiles) ----
    #pragma unroll
    for (int off = 32; off > 0; off >>= 1) {
        lossacc += __shfl_down(lossacc, off, 64);
        ssacc   += __shfl_down(ssacc,   off, 64);
    }
    if (lane == 0) { red[w] = lossacc; red[4 + w] = ssacc; }
    __syncthreads();
    if (t == 0) {
        atomicAdd(&slots[m & 1023], red[4] + red[5] + red[6]);
        float loss = (red[0] + red[1] + red[2]) * (1.f/150.f);
        out[(size_t)m*OSTR + 386] = loss;
        float imp = fv[m] - loss;
        imp = fminf(fmaxf(imp, -10000.f), 10000.f);
        out[(size_t)m*OSTR + 387] = imp;
    }
}

__global__ __launch_bounds__(256) void mlp_kernelB(float* __restrict__ slots)
{
    int t = threadIdx.x;
    float v = slots[t] + slots[t+256] + slots[t+512] + slots[t+768];
    #pragma unroll
    for (int off = 32; off > 0; off >>= 1) v += __shfl_down(v, off, 64);
    __shared__ float red[4];
    if ((t & 63) == 0) red[t >> 6] = v;
    __syncthreads();
    if (t == 0) {
        float total = red[0] + red[1] + red[2] + red[3];
        float coef = fminf(1.f, 10.f / (sqrtf(total) + 1e-6f));
        slots[1024] = coef;
    }
}

__global__ __launch_bounds__(256) void mlp_kernelC(float* __restrict__ out,
                                                   const float* __restrict__ slots,
                                                   int total)
{
    float coef = slots[1024];
    unsigned e = blockIdx.x * 256u + threadIdx.x;
    if (e < (unsigned)total) {
        unsigned m = e / 193u;
        unsigned i = e - m * 193u;
        size_t a = (size_t)m * OSTR + NPAR + i;
        out[a] *= coef;
    }
}

extern "C" void kernel_launch(void* const* d_in, const int* in_sizes, int n_in,
                              void* d_out, int out_size, void* d_ws, size_t ws_size,
                              hipStream_t stream) {
    const float* W1 = (const float*)d_in[0];
    const float* b1 = (const float*)d_in[1];
    const float* W2 = (const float*)d_in[2];
    const float* b2 = (const float*)d_in[3];
    const float* W3 = (const float*)d_in[4];
    const float* b3 = (const float*)d_in[5];
    const float* G1 = (const float*)d_in[6];
    const float* G2 = (const float*)d_in[7];
    const float* G3 = (const float*)d_in[8];
    const float* G4 = (const float*)d_in[9];
    const float* G5 = (const float*)d_in[10];
    const float* G6 = (const float*)d_in[11];
    const float* dx = (const float*)d_in[12];
    const float* fv = (const float*)d_in[13];
    const int*   dy = (const int*)d_in[14];
    const int*   st = (const int*)d_in[15];
    float* out   = (float*)d_out;
    float* slots = (float*)d_ws;

    int Bn = in_sizes[0] / 40;

    hipMemsetAsync(d_ws, 0, 4128, stream);                // sumsq slots + coef
    mlp_kernelA<<<Bn, 192, 0, stream>>>(W1,b1,W2,b2,W3,b3,
                                        G1,G2,G3,G4,G5,G6,
                                        dx,fv,dy,st,out,slots);
    mlp_kernelB<<<1, 256, 0, stream>>>(slots);
    int total = Bn * NPAR;
    mlp_kernelC<<<(total + 255)/256, 256, 0, stream>>>(out, slots, total);
}

// Round 4
// 296.436 us; speedup vs baseline: 1.7290x; 1.7290x over previous
//
#include <hip/hip_runtime.h>
#include <hip/hip_bf16.h>

#define NPTS 150
#define KP   168          // padded K for MFMA; 5 K-steps of 32 cover 0..159
#define NPAR 193
#define OSTR 388

// bf16 transposed activation buffers, element offsets into sT
#define H1T  0            // [11][168]  rows 0..9 = h1^T, row 10 = ones (db2)
#define H2T  1848         // [11][168]  rows 0..9 = h2^T, row 10 = ones (db3)
#define XT   3696         // [5][168]   rows 0..3 = x^T,  row 4  = ones (db1)
#define DZ2T 4536         // [10][168]
#define DZ1T 6216         // [10][168]
#define DLT  7896         // [3][168]
#define TTOT 8400

typedef __attribute__((ext_vector_type(8))) short short8;
typedef __attribute__((ext_vector_type(4))) float f32x4;

__constant__ float LRS[6] = {0.001f, 0.01f, 0.05f, 0.1f, 0.5f, 1.0f};

// 192 threads = 3 waves per MLP; one data point per thread; one dW MFMA tile
// per wave. waves_per_eu max=4 pins the VGPR budget at 128 so the ~110 live
// regs (wave-uniform W2/W3 arrays + activations) do NOT spill to scratch —
// round 3 showed the backend squeezing to 64 VGPR and paying 1.4 GB of HBM
// spill traffic for it.
__global__ __launch_bounds__(192)
__attribute__((amdgpu_waves_per_eu(2, 4)))
void mlp_kernelA(
    const float* __restrict__ W1, const float* __restrict__ b1,
    const float* __restrict__ W2, const float* __restrict__ b2,
    const float* __restrict__ W3, const float* __restrict__ b3,
    const float* __restrict__ G1, const float* __restrict__ G2,
    const float* __restrict__ G3, const float* __restrict__ G4,
    const float* __restrict__ G5, const float* __restrict__ G6,
    const float* __restrict__ dx, const float* __restrict__ fv,
    const int* __restrict__ dy, const int* __restrict__ stepsz,
    float* __restrict__ out, float* __restrict__ slots, int storeMode)
{
    const int m    = blockIdx.x;
    const int t    = threadIdx.x;
    const int lane = t & 63;
    const int w    = t >> 6;

    __shared__ alignas(16) __hip_bfloat16 sT[TTOT];
    __shared__ alignas(16) float sP[200];
    __shared__ float red[8];

    const float lr = LRS[stepsz[m]];

    // ---- SGD update: each thread computes param index t (t=0 also does 192) ----
    float pv;
    if      (t < 40)  pv = W1[m*40 + t]        - lr * G1[m*40 + t];
    else if (t < 50)  pv = b1[m*10 + (t-40)]   - lr * G2[m*10 + (t-40)];
    else if (t < 150) pv = W2[m*100 + (t-50)]  - lr * G3[m*100 + (t-50)];
    else if (t < 160) pv = b2[m*10 + (t-150)]  - lr * G4[m*10 + (t-150)];
    else if (t < 190) pv = W3[m*30 + (t-160)]  - lr * G5[m*30 + (t-160)];
    else              pv = b3[m*3 + (t-190)]   - lr * G6[m*3 + (t-190)];
    sP[t] = pv;
    out[(size_t)m*OSTR + t] = fminf(fmaxf(pv, -10000.f), 10000.f);
    if (t == 0) {
        float p192 = b3[m*3 + 2] - lr * G6[m*3 + 2];
        sP[192] = p192;
        out[(size_t)m*OSTR + 192] = fminf(fmaxf(p192, -10000.f), 10000.f);
    }

    // ---- zero the whole bf16 T-buffer (pad cols MUST be finite zeros:
    //      uninitialized LDS as bf16 can be Inf/NaN and 0*Inf = NaN in MFMA) ----
    {
        f32x4 z = {0.f, 0.f, 0.f, 0.f};
        f32x4* p = (f32x4*)sT;                 // 8400 bf16 = 1050 x 16B
        for (int i = t; i < 1050; i += 192) p[i] = z;
    }
    __syncthreads();

    // ---- ones rows (bias-grad columns) ----
    if (t < KP) {
        __hip_bfloat16 one = __float2bfloat16(1.0f);
        sT[H1T + 10*KP + t] = one;
        sT[H2T + 10*KP + t] = one;
        sT[XT  +  4*KP + t] = one;
    }
    // ---- x^T fill: x^T[f][n] = x[n][f] ----
    for (int i = t; i < 600; i += 192) {
        int n = i >> 2, f = i & 3;
        sT[XT + f*KP + n] = __float2bfloat16(dx[i]);
    }

    // ---- per-wave preload of wave-uniform params (broadcast LDS reads) ----
    float w2[10][10], bb2[10], w3[3][10], bb3[3], bb1[10];
    #pragma unroll
    for (int g = 0; g < 10; g++) {
        #pragma unroll
        for (int h = 0; h < 10; h++) w2[g][h] = sP[50 + g*10 + h];
        bb2[g] = sP[150 + g];
        bb1[g] = sP[40 + g];
    }
    #pragma unroll
    for (int o = 0; o < 3; o++) {
        #pragma unroll
        for (int g = 0; g < 10; g++) w3[o][g] = sP[160 + o*10 + g];
        bb3[o] = sP[190 + o];
    }
    const f32x4* sP4 = (const f32x4*)sP;   // W1 row j at sP4[j]

    // ================= fused forward + backward-dz: ONE point per thread =====
    float lossacc = 0.f, ssacc = 0.f;
    {
        const int  n   = t;
        const bool act = (n < NPTS);
        const int  nc  = act ? n : 0;

        f32x4 xv = ((const f32x4*)dx)[nc];
        int   yv = dy[nc];

        float h1v[10];
        #pragma unroll
        for (int j = 0; j < 10; j++) {
            f32x4 wv = sP4[j];
            float z = bb1[j] + xv.x*wv.x + xv.y*wv.y + xv.z*wv.z + xv.w*wv.w;
            h1v[j] = fmaxf(z, 0.f);
        }
        float h2v[10];
        #pragma unroll
        for (int g = 0; g < 10; g++) {
            float z = bb2[g];
            #pragma unroll
            for (int h = 0; h < 10; h++) z += h1v[h] * w2[g][h];
            h2v[g] = fmaxf(z, 0.f);
        }
        float lg[3];
        #pragma unroll
        for (int o = 0; o < 3; o++) {
            float z = bb3[o];
            #pragma unroll
            for (int g = 0; g < 10; g++) z += h2v[g] * w3[o][g];
            lg[o] = z;
        }
        float mx = fmaxf(lg[0], fmaxf(lg[1], lg[2]));
        float e0 = __expf(lg[0]-mx), e1 = __expf(lg[1]-mx), e2 = __expf(lg[2]-mx);
        float s   = e0 + e1 + e2;
        float inv = 1.f / s;
        float lse = mx + __logf(s);
        float ly  = (yv == 0) ? lg[0] : ((yv == 1) ? lg[1] : lg[2]);
        lossacc = act ? (lse - ly) : 0.f;

        float dl[3];
        dl[0] = (e0*inv - ((yv==0)?1.f:0.f)) * (1.f/150.f);
        dl[1] = (e1*inv - ((yv==1)?1.f:0.f)) * (1.f/150.f);
        dl[2] = (e2*inv - ((yv==2)?1.f:0.f)) * (1.f/150.f);

        float dz2v[10];
        #pragma unroll
        for (int g = 0; g < 10; g++) {
            float d = dl[0]*w3[0][g] + dl[1]*w3[1][g] + dl[2]*w3[2][g];
            dz2v[g] = (h2v[g] > 0.f) ? d : 0.f;
        }
        float dz1v[10];
        #pragma unroll
        for (int h = 0; h < 10; h++) {
            float d = 0.f;
            #pragma unroll
            for (int g = 0; g < 10; g++) d += dz2v[g] * w2[g][h];
            dz1v[h] = (h1v[h] > 0.f) ? d : 0.f;
        }

        if (act) {
            #pragma unroll
            for (int j = 0; j < 10; j++) sT[H1T  + j*KP + n] = __float2bfloat16(h1v[j]);
            #pragma unroll
            for (int g = 0; g < 10; g++) sT[H2T  + g*KP + n] = __float2bfloat16(h2v[g]);
            #pragma unroll
            for (int o = 0; o < 3;  o++) sT[DLT  + o*KP + n] = __float2bfloat16(dl[o]);
            #pragma unroll
            for (int g = 0; g < 10; g++) sT[DZ2T + g*KP + n] = __float2bfloat16(dz2v[g]);
            #pragma unroll
            for (int h = 0; h < 10; h++) sT[DZ1T + h*KP + n] = __float2bfloat16(dz1v[h]);
        }
    }
    __syncthreads();

    // ================= weight-grad GEMMs via MFMA: one tile per wave =========
    {
        const short* sTs = reinterpret_cast<const short*>(sT);
        const int mrow = lane & 15, q = lane >> 4;

        int abase, arows, bbase, bcols, woff, nW, boff;
        if      (w == 0) { abase=DZ2T; arows=10; bbase=H1T; bcols=11; woff=50;  nW=10; boff=150; }
        else if (w == 1) { abase=DZ1T; arows=10; bbase=XT;  bcols=5;  woff=0;   nW=4;  boff=40;  }
        else             { abase=DLT;  arows=3;  bbase=H2T; bcols=11; woff=160; nW=10; boff=190; }

        int ar = (mrow < arows) ? mrow : 0;
        int br = (mrow < bcols) ? mrow : 0;
        f32x4 acc = {0.f, 0.f, 0.f, 0.f};
        #pragma unroll
        for (int kk = 0; kk < 5; kk++) {
            int k0 = kk*32 + q*8;
            short8 a = *(const short8*)(sTs + abase + ar*KP + k0);
            short8 b = *(const short8*)(sTs + bbase + br*KP + k0);
            acc = __builtin_amdgcn_mfma_f32_16x16x32_bf16(a, b, acc, 0, 0, 0);
        }
        #pragma unroll
        for (int r = 0; r < 4; r++) {
            int row = q*4 + r;
            if (row < arows && mrow < bcols) {
                float v = acc[r];
                int off = (mrow < nW) ? (woff + row*nW + mrow) : (boff + row);
                out[(size_t)m*OSTR + NPAR + off] = v;   // raw grad; kernel C scales
                ssacc += v*v;
            }
        }
    }

    // ---- reductions: loss (across all 3 waves), sumsq (per-wave tiles) ----
    #pragma unroll
    for (int off = 32; off > 0; off >>= 1) {
        lossacc += __shfl_down(lossacc, off, 64);
        ssacc   += __shfl_down(ssacc,   off, 64);
    }
    if (lane == 0) { red[w] = lossacc; red[4 + w] = ssacc; }
    __syncthreads();
    if (t == 0) {
        float blockss = red[4] + red[5] + red[6];
        if (storeMode) slots[1 + m] = blockss;            // no memset needed
        else           atomicAdd(&slots[1 + (m & 1023)], blockss);
        float loss = (red[0] + red[1] + red[2]) * (1.f/150.f);
        out[(size_t)m*OSTR + 386] = loss;
        float imp = fv[m] - loss;
        imp = fminf(fmaxf(imp, -10000.f), 10000.f);
        out[(size_t)m*OSTR + 387] = imp;
    }
}

// Reduce slots[1..1+count) -> clip coef in slots[0].
__global__ __launch_bounds__(1024) void mlp_kernelB(float* __restrict__ slots, int count)
{
    int t = threadIdx.x;
    float v = 0.f;
    for (int i = t; i < count; i += 1024) v += slots[1 + i];
    #pragma unroll
    for (int off = 32; off > 0; off >>= 1) v += __shfl_down(v, off, 64);
    __shared__ float red[16];
    if ((t & 63) == 0) red[t >> 6] = v;
    __syncthreads();
    if (t == 0) {
        float total = 0.f;
        #pragma unroll
        for (int i = 0; i < 16; i++) total += red[i];
        slots[0] = fminf(1.f, 10.f / (sqrtf(total) + 1e-6f));
    }
}

__global__ __launch_bounds__(256) void mlp_kernelC(float* __restrict__ out,
                                                   const float* __restrict__ slots,
                                                   int total)
{
    float coef = slots[0];
    unsigned e = blockIdx.x * 256u + threadIdx.x;
    if (e < (unsigned)total) {
        unsigned m = e / 193u;
        unsigned i = e - m * 193u;
        size_t a = (size_t)m * OSTR + NPAR + i;
        out[a] *= coef;
    }
}

extern "C" void kernel_launch(void* const* d_in, const int* in_sizes, int n_in,
                              void* d_out, int out_size, void* d_ws, size_t ws_size,
                              hipStream_t stream) {
    const float* W1 = (const float*)d_in[0];
    const float* b1 = (const float*)d_in[1];
    const float* W2 = (const float*)d_in[2];
    const float* b2 = (const float*)d_in[3];
    const float* W3 = (const float*)d_in[4];
    const float* b3 = (const float*)d_in[5];
    const float* G1 = (const float*)d_in[6];
    const float* G2 = (const float*)d_in[7];
    const float* G3 = (const float*)d_in[8];
    const float* G4 = (const float*)d_in[9];
    const float* G5 = (const float*)d_in[10];
    const float* G6 = (const float*)d_in[11];
    const float* dx = (const float*)d_in[12];
    const float* fv = (const float*)d_in[13];
    const int*   dy = (const int*)d_in[14];
    const int*   st = (const int*)d_in[15];
    float* out   = (float*)d_out;
    float* slots = (float*)d_ws;

    int Bn = in_sizes[0] / 40;
    int storeMode = (ws_size >= (size_t)(Bn + 2) * sizeof(float)) ? 1 : 0;

    if (!storeMode) hipMemsetAsync(d_ws, 0, 4100, stream);
    mlp_kernelA<<<Bn, 192, 0, stream>>>(W1,b1,W2,b2,W3,b3,
                                        G1,G2,G3,G4,G5,G6,
                                        dx,fv,dy,st,out,slots,storeMode);
    mlp_kernelB<<<1, 1024, 0, stream>>>(slots, storeMode ? Bn : 1024);
    int total = Bn * NPAR;
    mlp_kernelC<<<(total + 255)/256, 256, 0, stream>>>(out, slots, total);
}